// Round 5
// baseline (1338.381 us; speedup 1.0000x reference)
//
#include <hip/hip_runtime.h>
#include <hip/hip_bf16.h>

// MultiViewFusion: the seq_len=1 MHA softmax is identically 1, so each MHA is
// (kv @ wv.T + bv) @ opw.T + opb. Fold everything up to the gates into two
// GEMMs: [ts|uc] = text @ M_text.T + b_text (K=768, N=256),
//        [tc|us] = user @ M_user.T + b_user (K=256, N=256).
// Then gates (sigmoid), mix, ff GEMM (K=256,N=256), LayerNorm+ReLU -> f32 out.
//
// Round-2 fixes vs round-1: (a) OUTPUT IS FLOAT32 (reference is fp32; round-1
// wrote bf16 into a float buffer -> absmax == max|ref|); (b) LDS cut from
// 96 KB to 48 KB (RB 16->8) to stay under the 64 KB per-workgroup limit;
// (c) folded weights repacked [K/4][N][4] so the inner loop does one float4
// weight load per thread.
// Rounds 3-5: identical source; rounds 2-4 all died on container infra
// (UnresponsiveContainer) before executing anything. Source re-audited
// (folding math, race structure, transpose indexing) while waiting.

namespace {

constexpr int RB = 8;  // rows per block

// workspace layout (floats)
constexpr int OFF_CW = 0;                        // CWt [4][128][128]  (CWt[i][d][o] = (opw_i @ wv_i)[o][d])
constexpr int OFF_CB = OFF_CW + 4 * 128 * 128;   // cv  [4][128]       (opw_i @ bv_i + opb_i)
constexpr int OFF_MT = OFF_CB + 4 * 128;         // MTt [768/4][256][4] (cols: [ts 0:128 | uc 128:256])
constexpr int OFF_BT = OFF_MT + 768 * 256;       // bT  [256]
constexpr int OFF_MU = OFF_BT + 256;             // MUt [256/4][256][4] (cols: [tc 0:128 | us 128:256])
constexpr int OFF_BU = OFF_MU + 256 * 256;       // bU  [256]
constexpr int OFF_TG = OFF_BU + 256;             // TGt [256/4][128][4]
constexpr int OFF_UG = OFF_TG + 256 * 128;       // UGt [256/4][128][4]
constexpr int OFF_FF = OFF_UG + 256 * 128;       // FFt [256/4][256][4]
constexpr int OFF_END = OFF_FF + 256 * 256;      // ~460k floats = 1.8 MB

// CWt[i][d][o] = sum_m opw[i][o][m] * ipw[i][256+m][d]   (wv rows of packed in_proj)
__global__ void k_combine(const float* __restrict__ ipw, const float* __restrict__ opw,
                          float* __restrict__ ws) {
  int n = blockIdx.x * 256 + threadIdx.x;  // 4*128*128 = 65536
  int i = n >> 14, o = (n >> 7) & 127, d = n & 127;
  const float* op = opw + i * 16384 + o * 128;
  const float* iv = ipw + i * 49152 + 256 * 128 + d;
  float s = 0.f;
#pragma unroll 4
  for (int m = 0; m < 128; ++m) s = fmaf(op[m], iv[m * 128], s);
  ws[OFF_CW + i * 16384 + d * 128 + o] = s;  // transposed store
}

// cv[i][o] = sum_m opw[i][o][m]*ipb[i][256+m] + opb[i][o]
__global__ void k_combine_bias(const float* __restrict__ ipb, const float* __restrict__ opb,
                               const float* __restrict__ opw, float* __restrict__ ws) {
  int t = blockIdx.x * 256 + threadIdx.x;  // 512
  int i = t >> 7, o = t & 127;
  const float* op = opw + i * 16384 + o * 128;
  const float* ib = ipb + i * 384 + 256;
  float s = opb[i * 128 + o];
#pragma unroll 4
  for (int m = 0; m < 128; ++m) s = fmaf(op[m], ib[m], s);
  ws[OFF_CB + t] = s;
}

// MTt: c<128 -> text_self row c = sum_d CWt[0][d][c]*tm_w[d][k]
//      c>=128 -> user_cross row (c-128) with CWt[3]
// stored interleaved: ws[OFF_MT + ((k>>2)*256 + c)*4 + (k&3)]
__global__ void k_mt(const float* __restrict__ tm_w, float* __restrict__ ws) {
  int n = blockIdx.x * 256 + threadIdx.x;  // 768*256
  int k = n >> 8, c = n & 255;
  const float* cw = ws + OFF_CW + ((c >> 7) ? 3 : 0) * 16384 + (c & 127);
  float s = 0.f;
#pragma unroll 4
  for (int d = 0; d < 128; ++d) s = fmaf(cw[d * 128], tm_w[d * 768 + k], s);
  ws[OFF_MT + (((k >> 2) * 256 + c) << 2) + (k & 3)] = s;
}

// MUt: c<128 -> text_cross (CWt[2] @ um_w), c>=128 -> user_self (CWt[1] @ um_w)
__global__ void k_mu(const float* __restrict__ um_w, float* __restrict__ ws) {
  int n = blockIdx.x * 256 + threadIdx.x;  // 256*256
  int k = n >> 8, c = n & 255;
  const float* cw = ws + OFF_CW + ((c >> 7) ? 1 : 2) * 16384 + (c & 127);
  float s = 0.f;
#pragma unroll 4
  for (int d = 0; d < 128; ++d) s = fmaf(cw[d * 128], um_w[d * 256 + k], s);
  ws[OFF_MU + (((k >> 2) * 256 + c) << 2) + (k & 3)] = s;
}

// bT[c] = CW_sel @ tm_b + cv_sel ; bU likewise with um_b
__global__ void k_bias_tu(const float* __restrict__ tm_b, const float* __restrict__ um_b,
                          float* __restrict__ ws) {
  int t = blockIdx.x * 256 + threadIdx.x;  // 512
  if (t < 256) {
    int sel = (t >> 7) ? 3 : 0;
    const float* cw = ws + OFF_CW + sel * 16384 + (t & 127);
    float s = ws[OFF_CB + sel * 128 + (t & 127)];
#pragma unroll 4
    for (int d = 0; d < 128; ++d) s = fmaf(cw[d * 128], tm_b[d], s);
    ws[OFF_BT + t] = s;
  } else {
    int c = t - 256;
    int sel = (c >> 7) ? 1 : 2;
    const float* cw = ws + OFF_CW + sel * 16384 + (c & 127);
    float s = ws[OFF_CB + sel * 128 + (c & 127)];
#pragma unroll 4
    for (int d = 0; d < 128; ++d) s = fmaf(cw[d * 128], um_b[d], s);
    ws[OFF_BU + c] = s;
  }
}

// dst[((k>>2)*R + o)*4 + (k&3)] = src[o*C + k]   (R = out-dim rows of src, C = K)
__global__ void k_transpose4(const float* __restrict__ src, float* __restrict__ dst,
                             int R, int C) {
  int n = blockIdx.x * 256 + threadIdx.x;
  if (n >= R * C) return;
  int o = n / C, k = n % C;
  dst[(((k >> 2) * R + o) << 2) + (k & 3)] = src[n];
}

// Fused main kernel: 256 threads, RB=8 rows per block. LDS = 48 KB.
// S layout per row: [ts 0:128 | tc 128:256 | us 256:384 | uc 384:512]
__launch_bounds__(256)
__global__ void k_main(const float* __restrict__ xt_g, const float* __restrict__ xu_g,
                       const float* __restrict__ ws,
                       const float* __restrict__ tg_b, const float* __restrict__ ug_b,
                       const float* __restrict__ ff_b, const float* __restrict__ ln_g,
                       const float* __restrict__ ln_b, float* __restrict__ out) {
  __shared__ float lds[RB * 768 + RB * 512 + RB * 256];  // 48 KB
  float* xt = lds;                        // [RB][768]; reused as H [RB][256] in phases 4-5
  float* S = lds + RB * 768;              // [RB][512]
  float* xu = lds + RB * 768 + RB * 512;  // [RB][256]; reused as F [RB][256] in phases 3-4

  const int t = threadIdx.x;
  const long row0 = (long)blockIdx.x * RB;

  // ---- phase 0: stage inputs (fully coalesced; LDS layout == global layout)
  {
    const float4* g = (const float4*)(xt_g + row0 * 768);
    float4* l = (float4*)xt;
#pragma unroll
    for (int it = 0; it < (RB * 768 / 4) / 256; ++it) l[it * 256 + t] = g[it * 256 + t];
    const float4* gu = (const float4*)(xu_g + row0 * 256);
    float4* lu = (float4*)xu;
#pragma unroll
    for (int it = 0; it < (RB * 256 / 4) / 256; ++it) lu[it * 256 + t] = gu[it * 256 + t];
  }
  __syncthreads();

  // ---- phase 1: text GEMM  [RB][768] @ MTt -> S cols {t<128: ts t} {t>=128: uc 256+t}
  {
    const float4* W4 = (const float4*)(ws + OFF_MT);
    float acc[RB];
#pragma unroll
    for (int r = 0; r < RB; ++r) acc[r] = 0.f;
    for (int k = 0; k < 768; k += 4) {
      float4 w = W4[(k >> 2) * 256 + t];
#pragma unroll
      for (int r = 0; r < RB; ++r) {
        float4 xv = *(const float4*)&xt[r * 768 + k];
        acc[r] = fmaf(w.x, xv.x, acc[r]);
        acc[r] = fmaf(w.y, xv.y, acc[r]);
        acc[r] = fmaf(w.z, xv.z, acc[r]);
        acc[r] = fmaf(w.w, xv.w, acc[r]);
      }
    }
    float bias = ws[OFF_BT + t];
    int d = (t < 128) ? t : (256 + t);
#pragma unroll
    for (int r = 0; r < RB; ++r) S[r * 512 + d] = acc[r] + bias;
  }
  // phases 1 and 2 write disjoint S columns and read distinct buffers: no barrier needed.

  // ---- phase 2: user GEMM  [RB][256] @ MUt -> S cols 128+t  (tc / us)
  {
    const float4* W4 = (const float4*)(ws + OFF_MU);
    float acc[RB];
#pragma unroll
    for (int r = 0; r < RB; ++r) acc[r] = 0.f;
    for (int k = 0; k < 256; k += 4) {
      float4 w = W4[(k >> 2) * 256 + t];
#pragma unroll
      for (int r = 0; r < RB; ++r) {
        float4 xv = *(const float4*)&xu[r * 256 + k];
        acc[r] = fmaf(w.x, xv.x, acc[r]);
        acc[r] = fmaf(w.y, xv.y, acc[r]);
        acc[r] = fmaf(w.z, xv.z, acc[r]);
        acc[r] = fmaf(w.w, xv.w, acc[r]);
      }
    }
    float bias = ws[OFF_BU + t];
#pragma unroll
    for (int r = 0; r < RB; ++r) S[r * 512 + 128 + t] = acc[r] + bias;
  }
  __syncthreads();

  // ---- phase 3: gates + mix -> F (xu region). half=0: tg over S[0:256]; half=1: ug over S[256:512]
  {
    int c = t & 127, half = t >> 7;
    const float4* W4 = (const float4*)(ws + (half ? OFF_UG : OFF_TG));
    const int so = half * 256;
    float acc[RB];
#pragma unroll
    for (int r = 0; r < RB; ++r) acc[r] = 0.f;
    for (int j = 0; j < 256; j += 4) {
      float4 w = W4[(j >> 2) * 128 + c];
#pragma unroll
      for (int r = 0; r < RB; ++r) {
        float4 sv = *(const float4*)&S[r * 512 + so + j];
        acc[r] = fmaf(w.x, sv.x, acc[r]);
        acc[r] = fmaf(w.y, sv.y, acc[r]);
        acc[r] = fmaf(w.z, sv.z, acc[r]);
        acc[r] = fmaf(w.w, sv.w, acc[r]);
      }
    }
    float gb = half ? ug_b[c] : tg_b[c];
    float* F = xu;
#pragma unroll
    for (int r = 0; r < RB; ++r) {
      float g = 1.f / (1.f + __expf(-(acc[r] + gb)));
      float a = S[r * 512 + so + c];        // self stream
      float b = S[r * 512 + so + 128 + c];  // cross stream
      F[r * 256 + half * 128 + c] = fmaf(g, b - a, a);  // a*(1-g)+b*g
    }
  }
  __syncthreads();

  // ---- phase 4: ff GEMM -> H (xt region, f32)
  {
    const float4* W4 = (const float4*)(ws + OFF_FF);
    const float* F = xu;
    float acc[RB];
#pragma unroll
    for (int r = 0; r < RB; ++r) acc[r] = 0.f;
    for (int j = 0; j < 256; j += 4) {
      float4 w = W4[(j >> 2) * 256 + t];
#pragma unroll
      for (int r = 0; r < RB; ++r) {
        float4 fv = *(const float4*)&F[r * 256 + j];
        acc[r] = fmaf(w.x, fv.x, acc[r]);
        acc[r] = fmaf(w.y, fv.y, acc[r]);
        acc[r] = fmaf(w.z, fv.z, acc[r]);
        acc[r] = fmaf(w.w, fv.w, acc[r]);
      }
    }
    float* H = xt;
    float bias = ff_b[t];
#pragma unroll
    for (int r = 0; r < RB; ++r) H[r * 256 + t] = acc[r] + bias;
  }
  __syncthreads();

  // ---- phase 5: LayerNorm + ReLU + f32 store. 32 threads per row, 8 elems each.
  {
    const float* H = xt;
    int r = t >> 5, q = t & 31;
    const float* Hr = H + r * 256 + q * 8;
    float s1 = 0.f, s2 = 0.f;
#pragma unroll
    for (int i = 0; i < 8; ++i) {
      float v = Hr[i];
      s1 += v;
      s2 += v * v;
    }
#pragma unroll
    for (int off = 1; off < 32; off <<= 1) {
      s1 += __shfl_xor(s1, off);
      s2 += __shfl_xor(s2, off);
    }
    float mu = s1 * (1.f / 256.f);
    float var = s2 * (1.f / 256.f) - mu * mu;
    float rstd = rsqrtf(var + 1e-5f);
    float* op = out + (row0 + r) * 256 + q * 8;
#pragma unroll
    for (int i = 0; i < 8; ++i) {
      float v = (Hr[i] - mu) * rstd * ln_g[q * 8 + i] + ln_b[q * 8 + i];
      op[i] = v > 0.f ? v : 0.f;
    }
  }
}

}  // namespace

extern "C" void kernel_launch(void* const* d_in, const int* in_sizes, int n_in,
                              void* d_out, int out_size, void* d_ws, size_t ws_size,
                              hipStream_t stream) {
  const float* text = (const float*)d_in[0];
  const float* user = (const float*)d_in[1];
  const float* tm_w = (const float*)d_in[2];
  const float* tm_b = (const float*)d_in[3];
  const float* um_w = (const float*)d_in[4];
  const float* um_b = (const float*)d_in[5];
  const float* ipw = (const float*)d_in[6];
  const float* ipb = (const float*)d_in[7];
  const float* opw = (const float*)d_in[8];
  const float* opb = (const float*)d_in[9];
  // d_in[10] = tg_w
  const float* tg_b = (const float*)d_in[11];
  // d_in[12] = ug_w
  const float* ug_b = (const float*)d_in[13];
  // d_in[14] = ff_w
  const float* ff_b = (const float*)d_in[15];
  const float* ln_g = (const float*)d_in[16];
  const float* ln_b = (const float*)d_in[17];
  float* ws = (float*)d_ws;
  float* out = (float*)d_out;

  // --- precompute folded weights (tiny, L2-resident)
  k_combine<<<4 * 128 * 128 / 256, 256, 0, stream>>>(ipw, opw, ws);
  k_combine_bias<<<2, 256, 0, stream>>>(ipb, opb, opw, ws);
  k_mt<<<768 * 256 / 256, 256, 0, stream>>>(tm_w, ws);
  k_mu<<<256 * 256 / 256, 256, 0, stream>>>(um_w, ws);
  k_bias_tu<<<2, 256, 0, stream>>>(tm_b, um_b, ws);
  k_transpose4<<<(128 * 256 + 255) / 256, 256, 0, stream>>>((const float*)d_in[10], ws + OFF_TG, 128, 256);
  k_transpose4<<<(128 * 256 + 255) / 256, 256, 0, stream>>>((const float*)d_in[12], ws + OFF_UG, 128, 256);
  k_transpose4<<<(256 * 256 + 255) / 256, 256, 0, stream>>>((const float*)d_in[14], ws + OFF_FF, 256, 256);

  // --- fused main kernel: 65536 rows / 8 per block
  k_main<<<65536 / RB, 256, 0, stream>>>(text, user, ws, tg_b, ug_b, ff_b, ln_g, ln_b, out);
}